// Round 12
// baseline (534.876 us; speedup 1.0000x reference)
//
#include <hip/hip_runtime.h>
#include <hip/hip_cooperative_groups.h>
#include <hip/hip_bf16.h>
#include <math.h>

namespace cg = cooperative_groups;

#define BB 2
#define LL 2048
#define EE 512
#define HH 8
#define DD 64
#define MM (BB * LL)   // 4096
#define LW (LL / 64)   // 32 k-tiles of 64

typedef short bf16x8 __attribute__((ext_vector_type(8)));
typedef float f32x4 __attribute__((ext_vector_type(4)));

#define MFMA16(a, b, c) __builtin_amdgcn_mfma_f32_16x16x32_bf16((a), (b), (c), 0, 0, 0)

#if __has_builtin(__builtin_amdgcn_exp2f)
#define EXP2(x) __builtin_amdgcn_exp2f(x)
#else
#define EXP2(x) exp2f(x)
#endif

// (1/sqrt(512)) * log2(e), folded into q projection
#define QSCALE 0.0637587146f

__device__ __forceinline__ uint4 cvt8_bf16(const float4 a, const float4 b) {
    union { __hip_bfloat16 h[8]; uint4 u; } t;
    t.h[0] = __float2bfloat16(a.x); t.h[1] = __float2bfloat16(a.y);
    t.h[2] = __float2bfloat16(a.z); t.h[3] = __float2bfloat16(a.w);
    t.h[4] = __float2bfloat16(b.x); t.h[5] = __float2bfloat16(b.y);
    t.h[6] = __float2bfloat16(b.z); t.h[7] = __float2bfloat16(b.w);
    return t.u;
}

struct GemmSmem {            // 49152 B
    __hip_bfloat16 As[2][2][64][32];
    __hip_bfloat16 Bs[2][2][128][32];
};
struct AttnSmem {            // 43520 B
    __hip_bfloat16 Ks[2][64][68];
    __hip_bfloat16 Vs[2][64][68];
    __hip_bfloat16 Ps[4][16][68];
};

struct FusedArgs {
    const float* X[3];
    const float* W[3];
    const float* bias[3];
    __hip_bfloat16* O[3];      // qb, kb, vtg
    const int* mask;
    unsigned long long* mbits;
    __hip_bfloat16* aob;
    const float* Wo;
    const float* bo;
    float* out;
};

// ---------------------------------------------------------------------------
// mode 0: single cooperative dispatch, grid 512 x 256 (2 blocks/CU at 48 KB
//   LDS, launch_bounds(256,2) -> VGPR<=256: big margin for the cooperative
//   occupancy validator that rejected r11's 768@3/CU).
//   Phase A: 768 QKV gemm tiles (<=2 per block) + mask ballot (64 rounds
//   exactly). grid.sync. Phase B: 512 attention tiles. grid.sync.
//   Phase C: 256 out-proj tiles.
// mode 1/2/3: phase A/B/C alone (plain-launch fallback if cooperative
//   launch is rejected; deterministic per environment).
// ---------------------------------------------------------------------------
__global__ __launch_bounds__(256, 2) void fused_all(FusedArgs p, int mode) {
    __shared__ alignas(16) char smem[sizeof(GemmSmem)];

    const int bid = blockIdx.x;
    const int tid = threadIdx.x;
    const int wave = tid >> 6, lane = tid & 63;
    const int l15 = lane & 15, quad = lane >> 4;

    // ======================= Phase A: QKV projections =======================
    if (mode == 0 || mode == 1) {
        GemmSmem& S = *reinterpret_cast<GemmSmem*>(smem);
        const int wn = wave * 32;
        const int arow = tid >> 2, acg = (tid & 3) * 16;
        const int ah = acg >> 5, ac = acg & 31;
        const int brow = tid >> 1, bcg = (tid & 1) * 32;
        const int bh = bcg >> 5;

        for (int t = bid; t < 768; t += 512) {
            const int z = t >> 8;           // 0..2
            const int r = t & 255;
            const int n0 = (r & 3) * 128;
            const int m0 = (r >> 2) * 64;

            const float* __restrict__ X = p.X[z];
            const float* __restrict__ W = p.W[z];
            const float* __restrict__ bias = p.bias[z];
            __hip_bfloat16* __restrict__ O = p.O[z];

            const float* Ax = X + (size_t)(m0 + arow) * EE + acg;
            const float* Bx = W + (size_t)(n0 + brow) * EE + bcg;

            f32x4 acc[4][2] = {};
            float4 ar[4], br[8];

            #define LOAD_A(k0)                                                 \
                ar[0] = *(const float4*)(Ax + (k0));                           \
                ar[1] = *(const float4*)(Ax + (k0) + 4);                       \
                ar[2] = *(const float4*)(Ax + (k0) + 8);                       \
                ar[3] = *(const float4*)(Ax + (k0) + 12);                      \
                br[0] = *(const float4*)(Bx + (k0));                           \
                br[1] = *(const float4*)(Bx + (k0) + 4);                       \
                br[2] = *(const float4*)(Bx + (k0) + 8);                       \
                br[3] = *(const float4*)(Bx + (k0) + 12);                      \
                br[4] = *(const float4*)(Bx + (k0) + 16);                      \
                br[5] = *(const float4*)(Bx + (k0) + 20);                      \
                br[6] = *(const float4*)(Bx + (k0) + 24);                      \
                br[7] = *(const float4*)(Bx + (k0) + 28);

            #define COMMIT_A(buf)                                              \
                *(uint4*)&S.As[buf][ah][arow][ac]     = cvt8_bf16(ar[0], ar[1]); \
                *(uint4*)&S.As[buf][ah][arow][ac + 8] = cvt8_bf16(ar[2], ar[3]); \
                *(uint4*)&S.Bs[buf][bh][brow][0]      = cvt8_bf16(br[0], br[1]); \
                *(uint4*)&S.Bs[buf][bh][brow][8]      = cvt8_bf16(br[2], br[3]); \
                *(uint4*)&S.Bs[buf][bh][brow][16]     = cvt8_bf16(br[4], br[5]); \
                *(uint4*)&S.Bs[buf][bh][brow][24]     = cvt8_bf16(br[6], br[7]);

            LOAD_A(0);
            COMMIT_A(0);
            __syncthreads();

            for (int kt = 0; kt < 8; ++kt) {
                const int cur = kt & 1;
                if (kt < 7) { LOAD_A((kt + 1) * 64); }

                #pragma unroll
                for (int c = 0; c < 2; ++c) {
                    bf16x8 af[4], bf2[2];
                    #pragma unroll
                    for (int i = 0; i < 4; ++i)
                        af[i] = *(const bf16x8*)&S.As[cur][c][i * 16 + l15][quad * 8];
                    #pragma unroll
                    for (int j = 0; j < 2; ++j)
                        bf2[j] = *(const bf16x8*)&S.Bs[cur][c][wn + j * 16 + l15][quad * 8];
                    #pragma unroll
                    for (int i = 0; i < 4; ++i)
                        #pragma unroll
                        for (int j = 0; j < 2; ++j)
                            acc[i][j] = MFMA16(af[i], bf2[j], acc[i][j]);
                }
                if (kt < 7) { COMMIT_A(cur ^ 1); }
                __syncthreads();
            }

            if (z == 2) {
                // V^T write: vtg[((b*HH+h)*DD+d)*LL + l]
                #pragma unroll
                for (int i = 0; i < 4; ++i)
                    #pragma unroll
                    for (int j = 0; j < 2; ++j) {
                        const int n = n0 + wn + j * 16 + l15;
                        const float bv = bias[n];
                        const int h = n >> 6, d = n & 63;
                        union { __hip_bfloat16 hh[4]; ushort4 v4; } pk;
                        #pragma unroll
                        for (int reg = 0; reg < 4; ++reg)
                            pk.hh[reg] = __float2bfloat16(acc[i][j][reg] + bv);
                        const int m = m0 + i * 16 + quad * 4;
                        const int bb = m >> 11, l = m & 2047;
                        *(ushort4*)&O[(((size_t)bb * HH + h) * DD + d) * LL + l] = pk.v4;
                    }
            } else {
                const float oscale = (z == 0) ? QSCALE : 1.0f;
                #pragma unroll
                for (int i = 0; i < 4; ++i)
                    #pragma unroll
                    for (int j = 0; j < 2; ++j) {
                        const int n = n0 + wn + j * 16 + l15;
                        const float bv = bias[n];
                        #pragma unroll
                        for (int reg = 0; reg < 4; ++reg) {
                            const int m = m0 + i * 16 + quad * 4 + reg;
                            O[(size_t)m * EE + n] =
                                __float2bfloat16((acc[i][j][reg] + bv) * oscale);
                        }
                    }
            }
        }

        // ---- mask ballot: 64 rounds x 512 blocks x 256 = 8,388,608 exact --
        for (int r = 0; r < 64; ++r) {
            const size_t idx = ((size_t)r * 512 + bid) * 256 + tid;
            const int m = p.mask[idx];
            const unsigned long long w = __ballot(m != 0);
            if ((tid & 63) == 0) p.mbits[idx >> 6] = w;
        }
    }

    if (mode == 0) {
        __threadfence();
        cg::this_grid().sync();
        __threadfence();
    }

    // ======================= Phase B: flash attention =======================
    if ((mode == 0 || mode == 2) && bid < 512) {
        AttnSmem& S = *reinterpret_cast<AttnSmem*>(smem);
        __syncthreads();  // LDS reuse boundary (phase A -> B)
        const int q0 = (bid & 31) * 64;
        const int h = (bid >> 5) & 7;
        const int b = bid >> 8;
        const int myq = q0 + wave * 16 + l15;

        const int srow = tid >> 2;
        const int scg = (tid & 3) * 16;

        bf16x8 qf[2];
        {
            const __hip_bfloat16* qrow =
                p.O[0] + ((size_t)b * LL + myq) * EE + h * DD;
            qf[0] = *(const bf16x8*)(qrow + quad * 8);
            qf[1] = *(const bf16x8*)(qrow + 32 + quad * 8);
        }

        bf16x8 ones8;
        #pragma unroll
        for (int e = 0; e < 8; ++e) ones8[e] = (short)0x3F80;  // bf16 1.0

        const __hip_bfloat16* kbase =
            p.O[1] + ((size_t)b * LL + srow) * EE + h * DD + scg;
        const __hip_bfloat16* vbase =
            p.O[2] + (((size_t)b * HH + h) * DD + srow) * LL + scg;
        const unsigned long long* mrow = p.mbits + ((size_t)b * LL + myq) * LW;

        f32x4 o[4] = {};
        f32x4 o4 = {};

        {
            uint4 k0a = *(const uint4*)(kbase);
            uint4 k0b = *(const uint4*)(kbase + 8);
            uint4 v0a = *(const uint4*)(vbase);
            uint4 v0b = *(const uint4*)(vbase + 8);
            *(uint4*)&S.Ks[0][srow][scg] = k0a;
            *(uint4*)&S.Ks[0][srow][scg + 8] = k0b;
            *(uint4*)&S.Vs[0][srow][scg] = v0a;
            *(uint4*)&S.Vs[0][srow][scg + 8] = v0b;
        }
        unsigned long long mw_cur = mrow[0];
        __syncthreads();

        for (int t = 0; t < LW; ++t) {
            const int cur = t & 1;
            const int nxt = cur ^ 1;
            const bool more = (t + 1) < LW;

            uint4 ka0, ka1, va0, va1;
            unsigned long long mw_n;
            if (more) {
                const __hip_bfloat16* kn = kbase + (size_t)(t + 1) * 64 * EE;
                const __hip_bfloat16* vn = vbase + (t + 1) * 64;
                ka0 = *(const uint4*)(kn);
                ka1 = *(const uint4*)(kn + 8);
                va0 = *(const uint4*)(vn);
                va1 = *(const uint4*)(vn + 8);
                mw_n = mrow[t + 1];
            }

            // S^T = K (Q*scale*log2e)^T
            f32x4 st[4] = {};
            #pragma unroll
            for (int mt = 0; mt < 4; ++mt) {
                bf16x8 a0 = *(const bf16x8*)&S.Ks[cur][mt * 16 + l15][quad * 8];
                bf16x8 a1 = *(const bf16x8*)&S.Ks[cur][mt * 16 + l15][32 + quad * 8];
                st[mt] = MFMA16(a0, qf[0], st[mt]);
                st[mt] = MFMA16(a1, qf[1], st[mt]);
            }

            // no-max softmax
            #pragma unroll
            for (int mt = 0; mt < 4; ++mt) {
                float pr[4];
                #pragma unroll
                for (int reg = 0; reg < 4; ++reg) {
                    const bool live = (mw_cur >> (mt * 16 + quad * 4 + reg)) & 1ull;
                    const float e = EXP2(st[mt][reg]);
                    pr[reg] = live ? e : 0.f;
                }
                union { __hip_bfloat162 h2[2]; ushort4 v; } pk;
                pk.h2[0] = __float22bfloat162_rn(make_float2(pr[0], pr[1]));
                pk.h2[1] = __float22bfloat162_rn(make_float2(pr[2], pr[3]));
                *(ushort4*)&S.Ps[wave][l15][mt * 16 + quad * 4] = pk.v;
            }

            // O += P V ; l += P @ ones
            bf16x8 pa0 = *(const bf16x8*)&S.Ps[wave][l15][quad * 8];
            bf16x8 pa1 = *(const bf16x8*)&S.Ps[wave][l15][32 + quad * 8];
            #pragma unroll
            for (int nt = 0; nt < 4; ++nt) {
                bf16x8 vb0 = *(const bf16x8*)&S.Vs[cur][nt * 16 + l15][quad * 8];
                bf16x8 vb1 = *(const bf16x8*)&S.Vs[cur][nt * 16 + l15][32 + quad * 8];
                o[nt] = MFMA16(pa0, vb0, o[nt]);
                o[nt] = MFMA16(pa1, vb1, o[nt]);
            }
            o4 = MFMA16(pa0, ones8, o4);
            o4 = MFMA16(pa1, ones8, o4);

            if (more) {
                *(uint4*)&S.Ks[nxt][srow][scg] = ka0;
                *(uint4*)&S.Ks[nxt][srow][scg + 8] = ka1;
                *(uint4*)&S.Vs[nxt][srow][scg] = va0;
                *(uint4*)&S.Vs[nxt][srow][scg + 8] = va1;
                mw_cur = mw_n;
            }
            __syncthreads();
        }

        float linvR[4];
        #pragma unroll
        for (int reg = 0; reg < 4; ++reg)
            linvR[reg] = 1.f / o4[reg];

        __hip_bfloat16* Ob =
            p.aob + ((size_t)b * LL + q0 + wave * 16) * EE + h * DD;
        #pragma unroll
        for (int nt = 0; nt < 4; ++nt)
            #pragma unroll
            for (int reg = 0; reg < 4; ++reg) {
                const int qrow = quad * 4 + reg;
                Ob[(size_t)qrow * EE + nt * 16 + l15] =
                    __float2bfloat16(o[nt][reg] * linvR[reg]);
            }
    }

    if (mode == 0) {
        __threadfence();
        cg::this_grid().sync();
        __threadfence();
    }

    // ======================= Phase C: output projection =====================
    if ((mode == 0 || mode == 3) && bid < 256) {
        GemmSmem& S = *reinterpret_cast<GemmSmem*>(smem);
        __syncthreads();  // LDS reuse boundary (phase B -> C)
        const int n0 = (bid & 3) * 128;
        const int m0 = (bid >> 2) * 64;
        const int wn = wave * 32;

        const int arow = tid >> 2, acg = (tid & 3) * 16;
        const int ah = acg >> 5, ac = acg & 31;
        const int brow = tid >> 1, bcg = (tid & 1) * 32;
        const int bh = bcg >> 5;
        const __hip_bfloat16* Ax = p.aob + (size_t)(m0 + arow) * EE + acg;
        const float* Bx = p.Wo + (size_t)(n0 + brow) * EE + bcg;

        f32x4 acc[4][2] = {};
        uint4 au[2];
        float4 br[8];

        #define LOAD_C(k0)                                                     \
            au[0] = *(const uint4*)(Ax + (k0));                                \
            au[1] = *(const uint4*)(Ax + (k0) + 8);                            \
            br[0] = *(const float4*)(Bx + (k0));                               \
            br[1] = *(const float4*)(Bx + (k0) + 4);                           \
            br[2] = *(const float4*)(Bx + (k0) + 8);                           \
            br[3] = *(const float4*)(Bx + (k0) + 12);                          \
            br[4] = *(const float4*)(Bx + (k0) + 16);                          \
            br[5] = *(const float4*)(Bx + (k0) + 20);                          \
            br[6] = *(const float4*)(Bx + (k0) + 24);                          \
            br[7] = *(const float4*)(Bx + (k0) + 28);

        #define COMMIT_C(buf)                                                  \
            *(uint4*)&S.As[buf][ah][arow][ac]     = au[0];                     \
            *(uint4*)&S.As[buf][ah][arow][ac + 8] = au[1];                     \
            *(uint4*)&S.Bs[buf][bh][brow][0]      = cvt8_bf16(br[0], br[1]);   \
            *(uint4*)&S.Bs[buf][bh][brow][8]      = cvt8_bf16(br[2], br[3]);   \
            *(uint4*)&S.Bs[buf][bh][brow][16]     = cvt8_bf16(br[4], br[5]);   \
            *(uint4*)&S.Bs[buf][bh][brow][24]     = cvt8_bf16(br[6], br[7]);

        LOAD_C(0);
        COMMIT_C(0);
        __syncthreads();

        for (int kt = 0; kt < 8; ++kt) {
            const int cur = kt & 1;
            if (kt < 7) { LOAD_C((kt + 1) * 64); }

            #pragma unroll
            for (int c = 0; c < 2; ++c) {
                bf16x8 af[4], bf2[2];
                #pragma unroll
                for (int i = 0; i < 4; ++i)
                    af[i] = *(const bf16x8*)&S.As[cur][c][i * 16 + l15][quad * 8];
                #pragma unroll
                for (int j = 0; j < 2; ++j)
                    bf2[j] = *(const bf16x8*)&S.Bs[cur][c][wn + j * 16 + l15][quad * 8];
                #pragma unroll
                for (int i = 0; i < 4; ++i)
                    #pragma unroll
                    for (int j = 0; j < 2; ++j)
                        acc[i][j] = MFMA16(af[i], bf2[j], acc[i][j]);
            }
            if (kt < 7) { COMMIT_C(cur ^ 1); }
            __syncthreads();
        }

        #pragma unroll
        for (int i = 0; i < 4; ++i)
            #pragma unroll
            for (int j = 0; j < 2; ++j) {
                const int n = n0 + wn + j * 16 + l15;
                const float bv = p.bo[n];
                #pragma unroll
                for (int reg = 0; reg < 4; ++reg) {
                    const int m = m0 + i * 16 + quad * 4 + reg;
                    p.out[(size_t)m * EE + n] = acc[i][j][reg] + bv;
                }
            }
    }
}

// ---------------------------------------------------------------------------
extern "C" void kernel_launch(void* const* d_in, const int* in_sizes, int n_in,
                              void* d_out, int out_size, void* d_ws, size_t ws_size,
                              hipStream_t stream) {
    const float* values = (const float*)d_in[0];
    const float* keys   = (const float*)d_in[1];
    const float* query  = (const float*)d_in[2];
    const int*   mask   = (const int*)d_in[3];
    const float* Wv = (const float*)d_in[4];
    const float* bv = (const float*)d_in[5];
    const float* Wk = (const float*)d_in[6];
    const float* bk = (const float*)d_in[7];
    const float* Wq = (const float*)d_in[8];
    const float* bq = (const float*)d_in[9];
    const float* Wo = (const float*)d_in[10];
    const float* bo = (const float*)d_in[11];
    float* out = (float*)d_out;

    const size_t XS = (size_t)MM * EE * 2;   // 4 MB bf16 [4096,512]
    char* w = (char*)d_ws;
    __hip_bfloat16* qb  = (__hip_bfloat16*)(w);
    __hip_bfloat16* kb  = (__hip_bfloat16*)(w + XS);
    __hip_bfloat16* vtg = (__hip_bfloat16*)(w + 2 * XS);
    __hip_bfloat16* aob = (__hip_bfloat16*)(w + 3 * XS);
    unsigned long long* mbits = (unsigned long long*)(w + 4 * XS);

    FusedArgs fa;
    fa.X[0] = query; fa.X[1] = keys; fa.X[2] = values;
    fa.W[0] = Wq;    fa.W[1] = Wk;   fa.W[2] = Wv;
    fa.bias[0] = bq; fa.bias[1] = bk; fa.bias[2] = bv;
    fa.O[0] = qb;    fa.O[1] = kb;   fa.O[2] = vtg;
    fa.mask = mask;  fa.mbits = mbits;
    fa.aob = aob;
    fa.Wo = Wo; fa.bo = bo; fa.out = out;

    int mode = 0;
    void* args[] = { &fa, &mode };
    hipError_t err = hipLaunchCooperativeKernel(
        (const void*)fused_all, dim3(512), dim3(256), args, 0, stream);

    if (err != hipSuccess) {
        // Deterministic fallback: same kernel, three plain phase launches.
        (void)hipGetLastError();  // clear sticky error
        fused_all<<<512, 256, 0, stream>>>(fa, 1);
        fused_all<<<512, 256, 0, stream>>>(fa, 2);
        fused_all<<<256, 256, 0, stream>>>(fa, 3);
    }
}

// Round 13
// 199.201 us; speedup vs baseline: 2.6851x; 2.6851x over previous
//
#include <hip/hip_runtime.h>
#include <hip/hip_bf16.h>
#include <math.h>

#define BB 2
#define LL 2048
#define EE 512
#define HH 8
#define DD 64
#define MM (BB * LL)   // 4096
#define LW (LL / 64)   // 32 k-tiles of 64

typedef short bf16x8 __attribute__((ext_vector_type(8)));
typedef float f32x4 __attribute__((ext_vector_type(4)));

#define MFMA16(a, b, c) __builtin_amdgcn_mfma_f32_16x16x32_bf16((a), (b), (c), 0, 0, 0)

#if __has_builtin(__builtin_amdgcn_exp2f)
#define EXP2(x) __builtin_amdgcn_exp2f(x)
#else
#define EXP2(x) exp2f(x)
#endif

// (1/sqrt(512)) * log2(e), folded into q projection
#define QSCALE 0.0637587146f

__device__ __forceinline__ uint4 cvt8_bf16(const float4 a, const float4 b) {
    union { __hip_bfloat16 h[8]; uint4 u; } t;
    t.h[0] = __float2bfloat16(a.x); t.h[1] = __float2bfloat16(a.y);
    t.h[2] = __float2bfloat16(a.z); t.h[3] = __float2bfloat16(a.w);
    t.h[4] = __float2bfloat16(b.x); t.h[5] = __float2bfloat16(b.y);
    t.h[6] = __float2bfloat16(b.z); t.h[7] = __float2bfloat16(b.w);
    return t.u;
}

// ---------------------------------------------------------------------------
// K0: mask int32 -> uint64 bitmask. 2048 blocks x 16 rounds x 256 lanes
// = 8,388,608 = BB*LL*LL exactly (r7-proven).
// ---------------------------------------------------------------------------
__global__ __launch_bounds__(256) void mask_to_bits(
    const int* __restrict__ mask, unsigned long long* __restrict__ bits) {
    const int mb = blockIdx.x;
    #pragma unroll
    for (int r = 0; r < 16; ++r) {
        const size_t idx = ((size_t)mb * 16 + r) * 256 + threadIdx.x;
        const int m = mask[idx];
        const unsigned long long w = __ballot(m != 0);
        if ((threadIdx.x & 63) == 0) bits[idx >> 6] = w;
    }
}

// ---------------------------------------------------------------------------
// K1: QKV projection, occupancy-first: 64x64 tile, BK=64, LDS 32 KB dbuf
// -> 4 blocks/CU (launch_bounds(256,4)); grid (8,64,3)=1536 blocks. fp32
// inputs converted to bf16 during staging (no separate cvt pass). Each wave
// computes 32x32 (2x2 frags, 8 MFMA/iter). z==0 folds QSCALE; z==2 writes
// V^T [B,H,D,L] directly from accumulators.
// ---------------------------------------------------------------------------
struct QKVArgs {
    const float* X[3];
    const float* W[3];
    const float* bias[3];
    __hip_bfloat16* O[3];   // qb, kb, vtg
};

__global__ __launch_bounds__(256, 4) void gemm_qkv(QKVArgs p) {
    __shared__ __hip_bfloat16 As[2][2][64][32];   // 16 KB
    __shared__ __hip_bfloat16 Bs[2][2][64][32];   // 16 KB

    const int z = blockIdx.z;
    const float* __restrict__ X = p.X[z];
    const float* __restrict__ W = p.W[z];
    const float* __restrict__ bias = p.bias[z];
    __hip_bfloat16* __restrict__ O = p.O[z];

    const int tid = threadIdx.x;
    const int wave = tid >> 6, lane = tid & 63;
    const int l15 = lane & 15, quad = lane >> 4;
    const int wr = (wave >> 1) * 32, wc = (wave & 1) * 32;
    const int m0 = blockIdx.y * 64, n0 = blockIdx.x * 64;

    const int row = tid >> 2, cg = (tid & 3) * 16;   // 16 floats/thread each
    const int kh = cg >> 5, kc = cg & 31;
    const float* Ax = X + (size_t)(m0 + row) * EE + cg;
    const float* Bx = W + (size_t)(n0 + row) * EE + cg;

    f32x4 acc[2][2] = {};
    float4 ar[4], br[4];

    #define LOAD_Q(k0)                                                         \
        ar[0] = *(const float4*)(Ax + (k0));                                   \
        ar[1] = *(const float4*)(Ax + (k0) + 4);                               \
        ar[2] = *(const float4*)(Ax + (k0) + 8);                               \
        ar[3] = *(const float4*)(Ax + (k0) + 12);                              \
        br[0] = *(const float4*)(Bx + (k0));                                   \
        br[1] = *(const float4*)(Bx + (k0) + 4);                               \
        br[2] = *(const float4*)(Bx + (k0) + 8);                               \
        br[3] = *(const float4*)(Bx + (k0) + 12);

    #define COMMIT_Q(buf)                                                      \
        *(uint4*)&As[buf][kh][row][kc]     = cvt8_bf16(ar[0], ar[1]);          \
        *(uint4*)&As[buf][kh][row][kc + 8] = cvt8_bf16(ar[2], ar[3]);          \
        *(uint4*)&Bs[buf][kh][row][kc]     = cvt8_bf16(br[0], br[1]);          \
        *(uint4*)&Bs[buf][kh][row][kc + 8] = cvt8_bf16(br[2], br[3]);

    LOAD_Q(0);
    COMMIT_Q(0);
    __syncthreads();

    for (int kt = 0; kt < 8; ++kt) {
        const int cur = kt & 1;
        if (kt < 7) { LOAD_Q((kt + 1) * 64); }

        #pragma unroll
        for (int c = 0; c < 2; ++c) {
            bf16x8 af[2], bf2[2];
            #pragma unroll
            for (int i = 0; i < 2; ++i)
                af[i] = *(const bf16x8*)&As[cur][c][wr + i * 16 + l15][quad * 8];
            #pragma unroll
            for (int j = 0; j < 2; ++j)
                bf2[j] = *(const bf16x8*)&Bs[cur][c][wc + j * 16 + l15][quad * 8];
            #pragma unroll
            for (int i = 0; i < 2; ++i)
                #pragma unroll
                for (int j = 0; j < 2; ++j)
                    acc[i][j] = MFMA16(af[i], bf2[j], acc[i][j]);
        }
        if (kt < 7) { COMMIT_Q(cur ^ 1); }
        __syncthreads();
    }

    if (z == 2) {
        // V^T write: vtg[((b*HH+h)*DD+d)*LL + l], 4 consecutive l per store
        #pragma unroll
        for (int i = 0; i < 2; ++i)
            #pragma unroll
            for (int j = 0; j < 2; ++j) {
                const int n = n0 + wc + j * 16 + l15;
                const float bv = bias[n];
                const int h = n >> 6, d = n & 63;
                union { __hip_bfloat16 hh[4]; ushort4 v4; } pk;
                #pragma unroll
                for (int reg = 0; reg < 4; ++reg)
                    pk.hh[reg] = __float2bfloat16(acc[i][j][reg] + bv);
                const int m = m0 + wr + i * 16 + quad * 4;
                const int bb = m >> 11, l = m & 2047;
                *(ushort4*)&O[(((size_t)bb * HH + h) * DD + d) * LL + l] = pk.v4;
            }
    } else {
        const float oscale = (z == 0) ? QSCALE : 1.0f;
        #pragma unroll
        for (int i = 0; i < 2; ++i)
            #pragma unroll
            for (int j = 0; j < 2; ++j) {
                const int n = n0 + wc + j * 16 + l15;
                const float bv = bias[n];
                #pragma unroll
                for (int reg = 0; reg < 4; ++reg) {
                    const int m = m0 + wr + i * 16 + quad * 4 + reg;
                    O[(size_t)m * EE + n] =
                        __float2bfloat16((acc[i][j][reg] + bv) * oscale);
                }
            }
    }
}

// ---------------------------------------------------------------------------
// K3: output projection, same 64x64 occupancy-first structure. A = aob
// (bf16, raw uint4 staging), B = Wo (fp32, cvt staging). Grid (8,64)=512.
// ---------------------------------------------------------------------------
__global__ __launch_bounds__(256, 4) void gemm_out(
    const __hip_bfloat16* __restrict__ X, const float* __restrict__ W,
    const float* __restrict__ bias, float* __restrict__ C) {
    __shared__ __hip_bfloat16 As[2][2][64][32];
    __shared__ __hip_bfloat16 Bs[2][2][64][32];

    const int tid = threadIdx.x;
    const int wave = tid >> 6, lane = tid & 63;
    const int l15 = lane & 15, quad = lane >> 4;
    const int wr = (wave >> 1) * 32, wc = (wave & 1) * 32;
    const int m0 = blockIdx.y * 64, n0 = blockIdx.x * 64;

    const int row = tid >> 2, cg = (tid & 3) * 16;
    const int kh = cg >> 5, kc = cg & 31;
    const __hip_bfloat16* Ax = X + (size_t)(m0 + row) * EE + cg;
    const float* Bx = W + (size_t)(n0 + row) * EE + cg;

    f32x4 acc[2][2] = {};
    uint4 au[2];
    float4 br[4];

    #define LOAD_O(k0)                                                         \
        au[0] = *(const uint4*)(Ax + (k0));                                    \
        au[1] = *(const uint4*)(Ax + (k0) + 8);                                \
        br[0] = *(const float4*)(Bx + (k0));                                   \
        br[1] = *(const float4*)(Bx + (k0) + 4);                               \
        br[2] = *(const float4*)(Bx + (k0) + 8);                               \
        br[3] = *(const float4*)(Bx + (k0) + 12);

    #define COMMIT_O(buf)                                                      \
        *(uint4*)&As[buf][kh][row][kc]     = au[0];                            \
        *(uint4*)&As[buf][kh][row][kc + 8] = au[1];                            \
        *(uint4*)&Bs[buf][kh][row][kc]     = cvt8_bf16(br[0], br[1]);          \
        *(uint4*)&Bs[buf][kh][row][kc + 8] = cvt8_bf16(br[2], br[3]);

    LOAD_O(0);
    COMMIT_O(0);
    __syncthreads();

    for (int kt = 0; kt < 8; ++kt) {
        const int cur = kt & 1;
        if (kt < 7) { LOAD_O((kt + 1) * 64); }

        #pragma unroll
        for (int c = 0; c < 2; ++c) {
            bf16x8 af[2], bf2[2];
            #pragma unroll
            for (int i = 0; i < 2; ++i)
                af[i] = *(const bf16x8*)&As[cur][c][wr + i * 16 + l15][quad * 8];
            #pragma unroll
            for (int j = 0; j < 2; ++j)
                bf2[j] = *(const bf16x8*)&Bs[cur][c][wc + j * 16 + l15][quad * 8];
            #pragma unroll
            for (int i = 0; i < 2; ++i)
                #pragma unroll
                for (int j = 0; j < 2; ++j)
                    acc[i][j] = MFMA16(af[i], bf2[j], acc[i][j]);
        }
        if (kt < 7) { COMMIT_O(cur ^ 1); }
        __syncthreads();
    }

    #pragma unroll
    for (int i = 0; i < 2; ++i)
        #pragma unroll
        for (int j = 0; j < 2; ++j) {
            const int n = n0 + wc + j * 16 + l15;
            const float bv = bias[n];
            #pragma unroll
            for (int reg = 0; reg < 4; ++reg) {
                const int m = m0 + wr + i * 16 + quad * 4 + reg;
                C[(size_t)m * EE + n] = acc[i][j][reg] + bv;
            }
        }
}

// ---------------------------------------------------------------------------
// K2: flash attention (r9/r12 structure, conflicts=0, l-via-MFMA).
// ---------------------------------------------------------------------------
__global__ __launch_bounds__(256) void attn_mfma(
    const __hip_bfloat16* __restrict__ Qb, const __hip_bfloat16* __restrict__ Kb,
    const __hip_bfloat16* __restrict__ vtg, const unsigned long long* __restrict__ mbits,
    __hip_bfloat16* __restrict__ Op) {
    __shared__ __hip_bfloat16 Ks[2][64][68];
    __shared__ __hip_bfloat16 Vs[2][64][68];
    __shared__ __hip_bfloat16 Ps[4][16][68];

    const int tid = threadIdx.x;
    const int wave = tid >> 6;
    const int lane = tid & 63;
    const int l15 = lane & 15;
    const int quad = lane >> 4;
    const int b = blockIdx.z;
    const int h = blockIdx.y;
    const int q0 = blockIdx.x * 64;
    const int myq = q0 + wave * 16 + l15;

    const int srow = tid >> 2;
    const int scg = (tid & 3) * 16;

    bf16x8 qf[2];
    {
        const __hip_bfloat16* qrow = Qb + ((size_t)b * LL + myq) * EE + h * DD;
        qf[0] = *(const bf16x8*)(qrow + quad * 8);
        qf[1] = *(const bf16x8*)(qrow + 32 + quad * 8);
    }

    bf16x8 ones8;
    #pragma unroll
    for (int e = 0; e < 8; ++e) ones8[e] = (short)0x3F80;  // bf16 1.0

    const __hip_bfloat16* kbase = Kb + ((size_t)b * LL + srow) * EE + h * DD + scg;
    const __hip_bfloat16* vbase = vtg + (((size_t)b * HH + h) * DD + srow) * LL + scg;
    const unsigned long long* mrow = mbits + ((size_t)b * LL + myq) * LW;

    f32x4 o[4] = {};
    f32x4 o4 = {};

    {
        uint4 k0a = *(const uint4*)(kbase);
        uint4 k0b = *(const uint4*)(kbase + 8);
        uint4 v0a = *(const uint4*)(vbase);
        uint4 v0b = *(const uint4*)(vbase + 8);
        *(uint4*)&Ks[0][srow][scg] = k0a;
        *(uint4*)&Ks[0][srow][scg + 8] = k0b;
        *(uint4*)&Vs[0][srow][scg] = v0a;
        *(uint4*)&Vs[0][srow][scg + 8] = v0b;
    }
    unsigned long long mw_cur = mrow[0];
    __syncthreads();

    for (int t = 0; t < LW; ++t) {
        const int cur = t & 1;
        const int nxt = cur ^ 1;
        const bool more = (t + 1) < LW;

        uint4 ka0, ka1, va0, va1;
        unsigned long long mw_n;
        if (more) {
            const __hip_bfloat16* kn = kbase + (size_t)(t + 1) * 64 * EE;
            const __hip_bfloat16* vn = vbase + (t + 1) * 64;
            ka0 = *(const uint4*)(kn);
            ka1 = *(const uint4*)(kn + 8);
            va0 = *(const uint4*)(vn);
            va1 = *(const uint4*)(vn + 8);
            mw_n = mrow[t + 1];
        }

        // S^T = K (Q*scale*log2e)^T
        f32x4 st[4] = {};
        #pragma unroll
        for (int mt = 0; mt < 4; ++mt) {
            bf16x8 a0 = *(const bf16x8*)&Ks[cur][mt * 16 + l15][quad * 8];
            bf16x8 a1 = *(const bf16x8*)&Ks[cur][mt * 16 + l15][32 + quad * 8];
            st[mt] = MFMA16(a0, qf[0], st[mt]);
            st[mt] = MFMA16(a1, qf[1], st[mt]);
        }

        // no-max softmax
        #pragma unroll
        for (int mt = 0; mt < 4; ++mt) {
            float pr[4];
            #pragma unroll
            for (int reg = 0; reg < 4; ++reg) {
                const bool live = (mw_cur >> (mt * 16 + quad * 4 + reg)) & 1ull;
                const float e = EXP2(st[mt][reg]);
                pr[reg] = live ? e : 0.f;
            }
            union { __hip_bfloat162 h2[2]; ushort4 v; } pk;
            pk.h2[0] = __float22bfloat162_rn(make_float2(pr[0], pr[1]));
            pk.h2[1] = __float22bfloat162_rn(make_float2(pr[2], pr[3]));
            *(ushort4*)&Ps[wave][l15][mt * 16 + quad * 4] = pk.v;
        }

        // O += P V ; l += P @ ones
        bf16x8 pa0 = *(const bf16x8*)&Ps[wave][l15][quad * 8];
        bf16x8 pa1 = *(const bf16x8*)&Ps[wave][l15][32 + quad * 8];
        #pragma unroll
        for (int nt = 0; nt < 4; ++nt) {
            bf16x8 vb0 = *(const bf16x8*)&Vs[cur][nt * 16 + l15][quad * 8];
            bf16x8 vb1 = *(const bf16x8*)&Vs[cur][nt * 16 + l15][32 + quad * 8];
            o[nt] = MFMA16(pa0, vb0, o[nt]);
            o[nt] = MFMA16(pa1, vb1, o[nt]);
        }
        o4 = MFMA16(pa0, ones8, o4);
        o4 = MFMA16(pa1, ones8, o4);

        if (more) {
            *(uint4*)&Ks[nxt][srow][scg] = ka0;
            *(uint4*)&Ks[nxt][srow][scg + 8] = ka1;
            *(uint4*)&Vs[nxt][srow][scg] = va0;
            *(uint4*)&Vs[nxt][srow][scg + 8] = va1;
            mw_cur = mw_n;
        }
        __syncthreads();
    }

    float linvR[4];
    #pragma unroll
    for (int reg = 0; reg < 4; ++reg)
        linvR[reg] = 1.f / o4[reg];

    __hip_bfloat16* Ob = Op + ((size_t)b * LL + q0 + wave * 16) * EE + h * DD;
    #pragma unroll
    for (int nt = 0; nt < 4; ++nt)
        #pragma unroll
        for (int reg = 0; reg < 4; ++reg) {
            const int qrow = quad * 4 + reg;
            Ob[(size_t)qrow * EE + nt * 16 + l15] =
                __float2bfloat16(o[nt][reg] * linvR[reg]);
        }
}

// ---------------------------------------------------------------------------
extern "C" void kernel_launch(void* const* d_in, const int* in_sizes, int n_in,
                              void* d_out, int out_size, void* d_ws, size_t ws_size,
                              hipStream_t stream) {
    const float* values = (const float*)d_in[0];
    const float* keys   = (const float*)d_in[1];
    const float* query  = (const float*)d_in[2];
    const int*   mask   = (const int*)d_in[3];
    const float* Wv = (const float*)d_in[4];
    const float* bv = (const float*)d_in[5];
    const float* Wk = (const float*)d_in[6];
    const float* bk = (const float*)d_in[7];
    const float* Wq = (const float*)d_in[8];
    const float* bq = (const float*)d_in[9];
    const float* Wo = (const float*)d_in[10];
    const float* bo = (const float*)d_in[11];
    float* out = (float*)d_out;

    const size_t XS = (size_t)MM * EE * 2;   // 4 MB bf16 [4096,512]
    char* w = (char*)d_ws;
    __hip_bfloat16* qb  = (__hip_bfloat16*)(w);
    __hip_bfloat16* kb  = (__hip_bfloat16*)(w + XS);
    __hip_bfloat16* vtg = (__hip_bfloat16*)(w + 2 * XS);
    __hip_bfloat16* aob = (__hip_bfloat16*)(w + 3 * XS);
    unsigned long long* mbits = (unsigned long long*)(w + 4 * XS);

    QKVArgs qa;
    qa.X[0] = query; qa.X[1] = keys; qa.X[2] = values;
    qa.W[0] = Wq;    qa.W[1] = Wk;   qa.W[2] = Wv;
    qa.bias[0] = bq; qa.bias[1] = bk; qa.bias[2] = bv;
    qa.O[0] = qb;    qa.O[1] = kb;   qa.O[2] = vtg;

    mask_to_bits<<<2048, 256, 0, stream>>>(mask, mbits);
    gemm_qkv<<<dim3(EE / 64, MM / 64, 3), 256, 0, stream>>>(qa);
    attn_mfma<<<dim3(LL / 64, HH, BB), 256, 0, stream>>>(qb, kb, vtg, mbits, aob);
    gemm_out<<<dim3(EE / 64, MM / 64), 256, 0, stream>>>(aob, Wo, bo, out);
}